// Round 11
// baseline (214.503 us; speedup 1.0000x reference)
//
#include <hip/hip_runtime.h>

#define N_NODES 50000
#define N_EDGES 800000
#define D 128

typedef __attribute__((ext_vector_type(8))) short bf16x8;
typedef __attribute__((ext_vector_type(4))) float f32x4;
typedef __attribute__((ext_vector_type(4))) short short4v;

__device__ __forceinline__ short f2bf(float f) {
    unsigned u = __float_as_uint(f);
    unsigned r = u + 0x7FFFu + ((u >> 16) & 1u);   // RNE; inputs finite
    return (short)(r >> 16);
}
__device__ __forceinline__ float bf2f(short s) {
    return __uint_as_float(((unsigned)(unsigned short)s) << 16);
}

// ---------------------------------------------------------------------------
// Phase 0: one-time W transpose+convert: Wt[c][k] = bf16(W[k][c]), 32 KB.
// Done ONCE instead of per-gemm-block (was 12.8M f2bf ops + 6.4M LDS
// bank-conflict cycles across 782 blocks). 8 blocks, one 16-k slice each.
// ---------------------------------------------------------------------------
__global__ __launch_bounds__(256) void prep_w(const float* __restrict__ W,
                                              short* __restrict__ Wt)
{
    __shared__ short Ls[128][17];    // [c][kk], padded -> conflict-free
    const int b = blockIdx.x;        // k-slice index (16 k's)
    const int t = threadIdx.x;
    #pragma unroll
    for (int i = 0; i < 8; ++i) {
        int lin = i * 256 + t;       // 0..2047
        int kk = lin >> 7;           // 0..15
        int c  = lin & 127;
        Ls[c][kk] = f2bf(W[(b * 16 + kk) * 128 + c]);   // coalesced read
    }
    __syncthreads();
    #pragma unroll
    for (int i = 0; i < 8; ++i) {
        int lin = i * 256 + t;       // 0..2047
        int c  = lin >> 4;           // 0..127
        int kk = lin & 15;
        Wt[c * 128 + b * 16 + kk] = Ls[c][kk];          // 32B-segment writes
    }
}

// ---------------------------------------------------------------------------
// Phase 1 (merged dispatch): blocks [0, nGemm) do support = inputs @ weight
// via bf16 MFMA; blocks [nGemm, ...) histogram rows. NO LDS: B-fragments are
// read directly from global Wt (32 KB = exactly L1-resident, reused by every
// block on the CU). A is read once per row, converted in-register.
// ---------------------------------------------------------------------------
__global__ __launch_bounds__(256) void gemm_hist_kernel(
    const float* __restrict__ inp, const short* __restrict__ Wt,
    short* __restrict__ support, const int* __restrict__ rows,
    int* __restrict__ counts, int nGemmBlocks)
{
    if ((int)blockIdx.x >= nGemmBlocks) {
        int e = ((int)blockIdx.x - nGemmBlocks) * 256 + threadIdx.x;
        if (e < N_EDGES) atomicAdd(&counts[rows[e]], 1);
        return;
    }

    const int tid = threadIdx.x;
    const int wid = tid >> 6, lane = tid & 63;
    const int lr = lane & 15;        // A-row / B-col / D-col
    const int lg = lane >> 4;        // k-group 0..3
    const int m0 = (int)blockIdx.x * 64 + wid * 16;

    int arow = m0 + lr;
    if (arow >= N_NODES) arow = 0;   // clamped rows feed only unstored D-rows
    const float* aptr = &inp[(size_t)arow * D + lg * 8];

    f32x4 acc[8] = {};
    #pragma unroll
    for (int kc = 0; kc < 4; ++kc) {
        float4 a0 = *(const float4*)(aptr + kc * 32);
        float4 a1 = *(const float4*)(aptr + kc * 32 + 4);
        bf16x8 af;
        af[0] = f2bf(a0.x); af[1] = f2bf(a0.y); af[2] = f2bf(a0.z); af[3] = f2bf(a0.w);
        af[4] = f2bf(a1.x); af[5] = f2bf(a1.y); af[6] = f2bf(a1.z); af[7] = f2bf(a1.w);
        #pragma unroll
        for (int t = 0; t < 8; ++t) {
            // B-frag elem j = W[k = kc*32+lg*8+j][c = t*16+lr] = Wt[c][k]
            const bf16x8 bf = *(const bf16x8*)&Wt[(t * 16 + lr) * 128 + kc * 32 + lg * 8];
            acc[t] = __builtin_amdgcn_mfma_f32_16x16x32_bf16(af, bf, acc[t], 0, 0, 0);
        }
    }
    // D: col = lane&15, row = (lane>>4)*4 + reg; store bf16
    #pragma unroll
    for (int t = 0; t < 8; ++t) {
        #pragma unroll
        for (int r = 0; r < 4; ++r) {
            int orow = m0 + lg * 4 + r;
            if (orow < N_NODES)
                support[(size_t)orow * D + t * 16 + lr] = f2bf(acc[t][r]);
        }
    }
}

// ---------------------------------------------------------------------------
// Phase 2b: single-dispatch exclusive scan. Ticket-ordered lookback with
// (flag,sum) packed into ONE 64-bit word -> relaxed spin only (agent-scope
// acquire spins invalidate L1/L2 every iteration -- round 6's 3x regression).
// ---------------------------------------------------------------------------
__global__ __launch_bounds__(256) void scan_fused(
    const int* __restrict__ counts, int* __restrict__ offsets,
    int* __restrict__ cursor, unsigned long long* __restrict__ aggFlag,
    int* __restrict__ ticket)
{
    __shared__ int s[256];
    __shared__ int bid_s, prefix_s;
    if (threadIdx.x == 0) bid_s = atomicAdd(ticket, 1);   // arrival order
    __syncthreads();
    const int bid = bid_s;
    const int gid = bid * 256 + threadIdx.x;
    int v = (gid < N_NODES) ? counts[gid] : 0;
    s[threadIdx.x] = v;
    __syncthreads();
    #pragma unroll
    for (int d = 1; d < 256; d <<= 1) {
        int t = (threadIdx.x >= d) ? s[threadIdx.x - d] : 0;
        __syncthreads();
        s[threadIdx.x] += t;
        __syncthreads();
    }
    if (threadIdx.x == 0) {
        unsigned long long pk = (1ULL << 63) | (unsigned long long)(unsigned)s[255];
        __hip_atomic_store(&aggFlag[bid], pk, __ATOMIC_RELAXED, __HIP_MEMORY_SCOPE_AGENT);
    }
    if (threadIdx.x < 64) {          // wave 0: lookback over predecessors
        int sum = 0;
        for (int j = threadIdx.x; j < bid; j += 64) {
            unsigned long long pk;
            while (((pk = __hip_atomic_load(&aggFlag[j], __ATOMIC_RELAXED,
                                            __HIP_MEMORY_SCOPE_AGENT)) >> 63) == 0)
                __builtin_amdgcn_s_sleep(1);
            sum += (int)(unsigned)(pk & 0xFFFFFFFFULL);
        }
        #pragma unroll
        for (int d = 1; d < 64; d <<= 1) sum += __shfl_xor(sum, d);
        if (threadIdx.x == 0) prefix_s = sum;
    }
    __syncthreads();
    if (gid < N_NODES) {
        int o = prefix_s + s[threadIdx.x] - v;
        offsets[gid] = o;
        cursor[gid] = o;
    }
    if (gid == 0) offsets[N_NODES] = N_EDGES;
}

// ---------------------------------------------------------------------------
// Phase 2c: XCD-partitioned scatter (round 9 measured 8x write amplification
// without it). Group g = bid&7 scans all edges, scatters only its 1/8 row
// range -> each CSR region written by one XCD, lines write back once.
// ---------------------------------------------------------------------------
#define SCAT_GROUPS 8
#define SCAT_BPG    392   // blocks per group; grid = 8 * 392 = 3136
__global__ __launch_bounds__(256) void scatter_kernel(
    const int* __restrict__ rows, const int* __restrict__ cols,
    const float* __restrict__ vals, int* __restrict__ cursor,
    int2* __restrict__ pairs)
{
    const int g  = blockIdx.x & (SCAT_GROUPS - 1);
    const int gi = blockIdx.x >> 3;
    const int rowLo = g * (N_NODES / SCAT_GROUPS);
    const int rowHi = rowLo + (N_NODES / SCAT_GROUPS);

    for (int e = gi * 256 + threadIdx.x; e < N_EDGES; e += SCAT_BPG * 256) {
        int r = rows[e];
        if (r >= rowLo && r < rowHi) {
            int p = atomicAdd(&cursor[r], 1);
            int2 pk;
            pk.x = cols[e];
            pk.y = __float_as_int(vals[e]);
            pairs[p] = pk;
        }
    }
}

// ---------------------------------------------------------------------------
// Phase 3: per-row gather-reduce on bf16 support + fused epilogue.
// One wave per row; two 32-lane halves each own 4 bf16 cols (8B gathers),
// 8-deep unroll per half = 16 gathers in flight per wave (latency-bound
// phase: round 5 showed VALU 30% / HBM 47%); cross-half shfl_xor(32) reduce.
// ---------------------------------------------------------------------------
__global__ __launch_bounds__(256) void agg_fused(
    const short* __restrict__ support, const int* __restrict__ offsets,
    const int2* __restrict__ pairs,
    const float* __restrict__ inp, const float* __restrict__ bias,
    const float* __restrict__ alpha, float* __restrict__ out)
{
    const int wv = (blockIdx.x * 256 + threadIdx.x) >> 6;
    const int lane = threadIdx.x & 63;
    if (wv >= N_NODES) return;
    const int half = lane >> 5;
    const int li = lane & 31;

    const int start = offsets[wv];
    const int end   = offsets[wv + 1];

    const float4 x = *(const float4*)&inp[(size_t)wv * D + li * 4];
    const float4 b4 = *(const float4*)&bias[li * 4];
    const float a0 = alpha[0], a1 = alpha[1];

    float4 acc = make_float4(0.f, 0.f, 0.f, 0.f);
    int e = start;
    for (; e + 16 <= end; e += 16) {     // 8 gathers in flight per half
        int2 p[8];
        #pragma unroll
        for (int j = 0; j < 8; ++j) p[j] = pairs[e + 2 * j + half];
        short4v s[8];
        #pragma unroll
        for (int j = 0; j < 8; ++j)
            s[j] = *(const short4v*)&support[(size_t)p[j].x * D + li * 4];
        #pragma unroll
        for (int j = 0; j < 8; ++j) {
            float v = __int_as_float(p[j].y);
            acc.x += v * bf2f(s[j][0]);
            acc.y += v * bf2f(s[j][1]);
            acc.z += v * bf2f(s[j][2]);
            acc.w += v * bf2f(s[j][3]);
        }
    }
    for (; e + 8 <= end; e += 8) {       // 4 in flight per half
        int2 p0 = pairs[e + 0 + half];
        int2 p1 = pairs[e + 2 + half];
        int2 p2 = pairs[e + 4 + half];
        int2 p3 = pairs[e + 6 + half];
        short4v s0 = *(const short4v*)&support[(size_t)p0.x * D + li * 4];
        short4v s1 = *(const short4v*)&support[(size_t)p1.x * D + li * 4];
        short4v s2 = *(const short4v*)&support[(size_t)p2.x * D + li * 4];
        short4v s3 = *(const short4v*)&support[(size_t)p3.x * D + li * 4];
        float v0 = __int_as_float(p0.y), v1 = __int_as_float(p1.y);
        float v2 = __int_as_float(p2.y), v3 = __int_as_float(p3.y);
        acc.x += v0 * bf2f(s0[0]) + v1 * bf2f(s1[0]) + v2 * bf2f(s2[0]) + v3 * bf2f(s3[0]);
        acc.y += v0 * bf2f(s0[1]) + v1 * bf2f(s1[1]) + v2 * bf2f(s2[1]) + v3 * bf2f(s3[1]);
        acc.z += v0 * bf2f(s0[2]) + v1 * bf2f(s1[2]) + v2 * bf2f(s2[2]) + v3 * bf2f(s3[2]);
        acc.w += v0 * bf2f(s0[3]) + v1 * bf2f(s1[3]) + v2 * bf2f(s2[3]) + v3 * bf2f(s3[3]);
    }
    for (; e < end; e += 2) {
        int idx = e + half;
        int2 p = (idx < end) ? pairs[idx] : make_int2(0, 0);   // v=0 when invalid
        float v = __int_as_float(p.y);
        short4v s = *(const short4v*)&support[(size_t)p.x * D + li * 4];
        acc.x += v * bf2f(s[0]);
        acc.y += v * bf2f(s[1]);
        acc.z += v * bf2f(s[2]);
        acc.w += v * bf2f(s[3]);
    }

    acc.x += __shfl_xor(acc.x, 32);
    acc.y += __shfl_xor(acc.y, 32);
    acc.z += __shfl_xor(acc.z, 32);
    acc.w += __shfl_xor(acc.w, 32);

    const float m = fmaxf(a0, a1);
    const float e0 = __expf(a0 - m), e1 = __expf(a1 - m);
    const float inv = 1.f / (e0 + e1);
    const float g0 = e0 * inv, g1 = e1 * inv;

    float t0 = acc.x * g0 + x.x * g1 + b4.x;
    float t1 = acc.y * g0 + x.y * g1 + b4.y;
    float t2 = acc.z * g0 + x.z * g1 + b4.z;
    float t3 = acc.w * g0 + x.w * g1 + b4.w;
    float r0 = t0 > 0.f ? t0 : (__expf(t0) - 1.f);
    float r1 = t1 > 0.f ? t1 : (__expf(t1) - 1.f);
    float r2 = t2 > 0.f ? t2 : (__expf(t2) - 1.f);
    float r3 = t3 > 0.f ? t3 : (__expf(t3) - 1.f);

    float2 o = (half == 0) ? make_float2(r0, r1) : make_float2(r2, r3);
    *(float2*)&out[(size_t)wv * D + li * 4 + half * 2] = o;
}

extern "C" void kernel_launch(void* const* d_in, const int* in_sizes, int n_in,
                              void* d_out, int out_size, void* d_ws, size_t ws_size,
                              hipStream_t stream)
{
    const float* inp   = (const float*)d_in[0];
    const float* W     = (const float*)d_in[1];
    const float* bias  = (const float*)d_in[2];
    const float* alpha = (const float*)d_in[3];
    const float* vals  = (const float*)d_in[4];
    const int*   rows  = (const int*)d_in[5];
    const int*   cols  = (const int*)d_in[6];
    float* out = (float*)d_out;

    // workspace layout (~20 MB; no trailing backslashes in comments)
    short* support  = (short*)d_ws;                            // N*D bf16 (16B-aligned)
    short* Wt       = support + (size_t)N_NODES * D;           // 128*128 bf16 (16B-aligned)
    int*   counts   = (int*)(Wt + 128 * 128);                  // N ints (memset)
    int*   ticket   = counts + N_NODES;                        // 1 int (memset)
    // +1 pad keeps aggFlag 8B-aligned
    unsigned long long* aggFlag = (unsigned long long*)(ticket + 2); // 256 x 8B (memset)
    int*   offsets  = (int*)(aggFlag + 256);                   // N+1 ints
    int*   cursor   = offsets + N_NODES + 1;                   // N ints (+1 pad -> 8B align)
    int2*  pairs    = (int2*)(cursor + N_NODES + 1);           // E pairs, 8B-aligned

    const int nGemmBlocks = (N_NODES + 63) / 64;            // 782
    const int nEdgeBlocks = (N_EDGES + 255) / 256;          // 3125
    const int nScanBlocks = (N_NODES + 255) / 256;          // 196

    // zero counts + ticket + pad + aggFlag in one contiguous memset
    (void)hipMemsetAsync(counts, 0, (size_t)(N_NODES + 2 + 512) * sizeof(int), stream);

    prep_w<<<8, 256, 0, stream>>>(W, Wt);
    gemm_hist_kernel<<<nGemmBlocks + nEdgeBlocks, 256, 0, stream>>>(
        inp, Wt, support, rows, counts, nGemmBlocks);
    scan_fused<<<nScanBlocks, 256, 0, stream>>>(counts, offsets, cursor,
                                                aggFlag, ticket);
    scatter_kernel<<<SCAT_GROUPS * SCAT_BPG, 256, 0, stream>>>(
        rows, cols, vals, cursor, pairs);
    agg_fused<<<(N_NODES * 64 + 255) / 256, 256, 0, stream>>>(
        support, offsets, pairs, inp, bias, alpha, out);
}

// Round 13
// 171.138 us; speedup vs baseline: 1.2534x; 1.2534x over previous
//
#include <hip/hip_runtime.h>

#define N_NODES 50000
#define N_EDGES 800000
#define D 128
#define CAP 128           // bucket capacity (pairs/row); deg~Poisson(16), P(>=128)~e^-100

typedef __attribute__((ext_vector_type(8))) short bf16x8;
typedef __attribute__((ext_vector_type(4))) float f32x4;
typedef __attribute__((ext_vector_type(4))) short short4v;

__device__ __forceinline__ short f2bf(float f) {
    unsigned u = __float_as_uint(f);
    unsigned r = u + 0x7FFFu + ((u >> 16) & 1u);   // RNE; inputs finite
    return (short)(r >> 16);
}
__device__ __forceinline__ float bf2f(short s) {
    return __uint_as_float(((unsigned)(unsigned short)s) << 16);
}

// ---------------------------------------------------------------------------
// Merged dispatch 1: blocks [0, nGemm) = support = inputs @ weight (bf16 MFMA,
// LDS W-staging, r10-proven); blocks [nGemm, ...) = direct bucket scatter.
//
// Bucket scatter replaces hist+scan+CSR-scatter: atomicAdd(&cnt[r],1) IS the
// insertion cursor; edge lands at buckets[r*CAP + p]. XCD-partitioned as in
// r10 (group g = sbid&7 scans all edges, keeps rows in its 1/8 range) so each
// bucket region is written by one XCD -> single writeback per line (r9
// measured 8x write amplification without this).
// ---------------------------------------------------------------------------
#define SCAT_GROUPS 8
#define SCAT_BPG    392   // blocks per group; scatter grid = 8*392 = 3136
__global__ __launch_bounds__(256) void gemm_scatter_kernel(
    const float* __restrict__ inp, const float* __restrict__ W,
    short* __restrict__ support,
    const int* __restrict__ rows, const int* __restrict__ cols,
    const float* __restrict__ vals,
    int* __restrict__ cnt, int2* __restrict__ buckets, int nGemmBlocks)
{
    if ((int)blockIdx.x >= nGemmBlocks) {
        // ---------------- bucket scatter ----------------
        const int sbid = (int)blockIdx.x - nGemmBlocks;
        const int g  = sbid & (SCAT_GROUPS - 1);
        const int gi = sbid >> 3;
        const int rowLo = g * (N_NODES / SCAT_GROUPS);
        const int rowHi = rowLo + (N_NODES / SCAT_GROUPS);
        for (int e = gi * 256 + threadIdx.x; e < N_EDGES; e += SCAT_BPG * 256) {
            int r = rows[e];
            if (r >= rowLo && r < rowHi) {
                int p = atomicAdd(&cnt[r], 1);
                if (p < CAP) {                    // overflow guard (never in practice)
                    int2 pk;
                    pk.x = cols[e];
                    pk.y = __float_as_int(vals[e]);
                    buckets[(size_t)r * CAP + p] = pk;
                }
            }
        }
        return;
    }

    // ---------------- GEMM (r10-proven form) ----------------
    __shared__ short Wt[128][136];   // 34 KB: Wt[col][k] bf16 (padded rows)
    const int tid = threadIdx.x;

    #pragma unroll
    for (int i = 0; i < 16; ++i) {
        int lin = i * 1024 + tid * 4;        // linear into W[k][c]
        int k = lin >> 7, c = lin & 127;
        float4 w = *(const float4*)&W[lin];
        Wt[c + 0][k] = f2bf(w.x);
        Wt[c + 1][k] = f2bf(w.y);
        Wt[c + 2][k] = f2bf(w.z);
        Wt[c + 3][k] = f2bf(w.w);
    }
    __syncthreads();

    const int wid = tid >> 6, lane = tid & 63;
    const int lr = lane & 15;        // A-row / B-col / D-col
    const int lg = lane >> 4;        // k-group 0..3
    const int m0 = (int)blockIdx.x * 64 + wid * 16;

    int arow = m0 + lr;
    if (arow >= N_NODES) arow = 0;   // clamped rows feed only unstored D-rows
    const float* aptr = &inp[(size_t)arow * D + lg * 8];

    f32x4 acc[8] = {};
    #pragma unroll
    for (int kc = 0; kc < 4; ++kc) {
        float4 a0 = *(const float4*)(aptr + kc * 32);
        float4 a1 = *(const float4*)(aptr + kc * 32 + 4);
        bf16x8 af;
        af[0] = f2bf(a0.x); af[1] = f2bf(a0.y); af[2] = f2bf(a0.z); af[3] = f2bf(a0.w);
        af[4] = f2bf(a1.x); af[5] = f2bf(a1.y); af[6] = f2bf(a1.z); af[7] = f2bf(a1.w);
        #pragma unroll
        for (int t = 0; t < 8; ++t) {
            const bf16x8 bf = *(const bf16x8*)&Wt[t * 16 + lr][kc * 32 + lg * 8];
            acc[t] = __builtin_amdgcn_mfma_f32_16x16x32_bf16(af, bf, acc[t], 0, 0, 0);
        }
    }
    // D: col = lane&15, row = (lane>>4)*4 + reg; store bf16
    #pragma unroll
    for (int t = 0; t < 8; ++t) {
        #pragma unroll
        for (int r = 0; r < 4; ++r) {
            int orow = m0 + lg * 4 + r;
            if (orow < N_NODES)
                support[(size_t)orow * D + t * 16 + lr] = f2bf(acc[t][r]);
        }
    }
}

// ---------------------------------------------------------------------------
// Dispatch 2: per-row gather-reduce on bf16 support + fused epilogue.
// One wave per row; two 32-lane halves each own 4 bf16 cols (8B gathers),
// 4-deep unroll = 8 gathers in flight per wave (r10-proven depth);
// cross-half shfl_xor(32) reduce; coalesced float2 store.
// Row wv's edges: buckets[wv*CAP .. wv*CAP + min(cnt[wv],CAP)).
// ---------------------------------------------------------------------------
__global__ __launch_bounds__(256) void agg_fused(
    const short* __restrict__ support, const int* __restrict__ cnt,
    const int2* __restrict__ buckets,
    const float* __restrict__ inp, const float* __restrict__ bias,
    const float* __restrict__ alpha, float* __restrict__ out)
{
    const int wv = (blockIdx.x * 256 + threadIdx.x) >> 6;
    const int lane = threadIdx.x & 63;
    if (wv >= N_NODES) return;
    const int half = lane >> 5;
    const int li = lane & 31;

    int n = cnt[wv];
    if (n > CAP) n = CAP;
    const int start = wv * CAP;
    const int end   = start + n;

    const float4 x = *(const float4*)&inp[(size_t)wv * D + li * 4];
    const float4 b4 = *(const float4*)&bias[li * 4];
    const float a0 = alpha[0], a1 = alpha[1];

    float4 acc = make_float4(0.f, 0.f, 0.f, 0.f);
    int e = start;
    for (; e + 8 <= end; e += 8) {       // 4 gathers in flight per half
        int2 p0 = buckets[e + 0 + half];
        int2 p1 = buckets[e + 2 + half];
        int2 p2 = buckets[e + 4 + half];
        int2 p3 = buckets[e + 6 + half];
        short4v s0 = *(const short4v*)&support[(size_t)p0.x * D + li * 4];
        short4v s1 = *(const short4v*)&support[(size_t)p1.x * D + li * 4];
        short4v s2 = *(const short4v*)&support[(size_t)p2.x * D + li * 4];
        short4v s3 = *(const short4v*)&support[(size_t)p3.x * D + li * 4];
        float v0 = __int_as_float(p0.y), v1 = __int_as_float(p1.y);
        float v2 = __int_as_float(p2.y), v3 = __int_as_float(p3.y);
        acc.x += v0 * bf2f(s0[0]) + v1 * bf2f(s1[0]) + v2 * bf2f(s2[0]) + v3 * bf2f(s3[0]);
        acc.y += v0 * bf2f(s0[1]) + v1 * bf2f(s1[1]) + v2 * bf2f(s2[1]) + v3 * bf2f(s3[1]);
        acc.z += v0 * bf2f(s0[2]) + v1 * bf2f(s1[2]) + v2 * bf2f(s2[2]) + v3 * bf2f(s3[2]);
        acc.w += v0 * bf2f(s0[3]) + v1 * bf2f(s1[3]) + v2 * bf2f(s2[3]) + v3 * bf2f(s3[3]);
    }
    for (; e < end; e += 2) {
        int idx = e + half;
        int2 p = (idx < end) ? buckets[idx] : make_int2(0, 0);  // v=0 when invalid
        float v = __int_as_float(p.y);
        short4v s = *(const short4v*)&support[(size_t)p.x * D + li * 4];
        acc.x += v * bf2f(s[0]);
        acc.y += v * bf2f(s[1]);
        acc.z += v * bf2f(s[2]);
        acc.w += v * bf2f(s[3]);
    }

    acc.x += __shfl_xor(acc.x, 32);
    acc.y += __shfl_xor(acc.y, 32);
    acc.z += __shfl_xor(acc.z, 32);
    acc.w += __shfl_xor(acc.w, 32);

    const float m = fmaxf(a0, a1);
    const float e0 = __expf(a0 - m), e1 = __expf(a1 - m);
    const float inv = 1.f / (e0 + e1);
    const float g0 = e0 * inv, g1 = e1 * inv;

    float t0 = acc.x * g0 + x.x * g1 + b4.x;
    float t1 = acc.y * g0 + x.y * g1 + b4.y;
    float t2 = acc.z * g0 + x.z * g1 + b4.z;
    float t3 = acc.w * g0 + x.w * g1 + b4.w;
    float r0 = t0 > 0.f ? t0 : (__expf(t0) - 1.f);
    float r1 = t1 > 0.f ? t1 : (__expf(t1) - 1.f);
    float r2 = t2 > 0.f ? t2 : (__expf(t2) - 1.f);
    float r3 = t3 > 0.f ? t3 : (__expf(t3) - 1.f);

    float2 o = (half == 0) ? make_float2(r0, r1) : make_float2(r2, r3);
    *(float2*)&out[(size_t)wv * D + li * 4 + half * 2] = o;
}

extern "C" void kernel_launch(void* const* d_in, const int* in_sizes, int n_in,
                              void* d_out, int out_size, void* d_ws, size_t ws_size,
                              hipStream_t stream)
{
    const float* inp   = (const float*)d_in[0];
    const float* W     = (const float*)d_in[1];
    const float* bias  = (const float*)d_in[2];
    const float* alpha = (const float*)d_in[3];
    const float* vals  = (const float*)d_in[4];
    const int*   rows  = (const int*)d_in[5];
    const int*   cols  = (const int*)d_in[6];
    float* out = (float*)d_out;

    // workspace layout (~64.3 MB; no trailing backslashes in comments)
    short* support = (short*)d_ws;                            // N*D bf16
    int*   cnt     = (int*)(support + (size_t)N_NODES * D);   // N ints (memset)
    // N even -> buckets stays 8B-aligned
    int2*  buckets = (int2*)(cnt + N_NODES);                  // N*CAP pairs, 51.2 MB

    const int nGemmBlocks = (N_NODES + 63) / 64;              // 782
    const int nScatBlocks = SCAT_GROUPS * SCAT_BPG;           // 3136

    // zero cnt (doubles as histogram AND insertion cursor)
    (void)hipMemsetAsync(cnt, 0, (size_t)N_NODES * sizeof(int), stream);

    gemm_scatter_kernel<<<nGemmBlocks + nScatBlocks, 256, 0, stream>>>(
        inp, W, support, rows, cols, vals, cnt, buckets, nGemmBlocks);
    agg_fused<<<(N_NODES * 64 + 255) / 256, 256, 0, stream>>>(
        support, cnt, buckets, inp, bias, alpha, out);
}